// Round 10
// baseline (387.631 us; speedup 1.0000x reference)
//
#include <hip/hip_runtime.h>

typedef unsigned short u16;
typedef unsigned int u32;
using bf16x8 = __attribute__((ext_vector_type(8))) short;
using f32x4  = __attribute__((ext_vector_type(4))) float;

#define B_ 64
#define S_ 400
#define E_ 128
#define H_ 512
#define M_ 512
#define R_ (B_ * S_)   // 25600

__device__ __forceinline__ float b2f(u16 u){
  union { u32 i; float f; } c; c.i = ((u32)u) << 16; return c.f;
}
__device__ __forceinline__ u16 f2b(float f){
  union { u32 i; float f; } c; c.f = f;
  u32 r = c.i + 0x7FFFu + ((c.i >> 16) & 1u);
  return (u16)(r >> 16);
}
__device__ __forceinline__ float sigm(float x){ return 1.0f / (1.0f + __expf(-x)); }
__device__ __forceinline__ float fast_tanh(float x){
  float e = __expf(2.0f * x);
  return 1.0f - 2.0f / (e + 1.0f);
}
// pack 8 consecutive fp32 -> bf16x8 (truncate: take high u16 of each fp32)
__device__ __forceinline__ bf16x8 pack8(const float* __restrict__ p){
  const u32* u = (const u32*)p;
  union { u32 w[4]; bf16x8 v; } c;
  c.w[0] = (u[1] & 0xFFFF0000u) | (u[0] >> 16);
  c.w[1] = (u[3] & 0xFFFF0000u) | (u[2] >> 16);
  c.w[2] = (u[5] & 0xFFFF0000u) | (u[4] >> 16);
  c.w[3] = (u[7] & 0xFFFF0000u) | (u[6] >> 16);
  return c.v;
}
// pack two float4 (8 consecutive fp32) -> bf16x8, same truncation as pack8
__device__ __forceinline__ bf16x8 pack8r(float4 a, float4 b){
  union { u32 w[4]; bf16x8 v; } c;
  c.w[0] = (__float_as_uint(a.y) & 0xFFFF0000u) | (__float_as_uint(a.x) >> 16);
  c.w[1] = (__float_as_uint(a.w) & 0xFFFF0000u) | (__float_as_uint(a.z) >> 16);
  c.w[2] = (__float_as_uint(b.y) & 0xFFFF0000u) | (__float_as_uint(b.x) >> 16);
  c.w[3] = (__float_as_uint(b.w) & 0xFFFF0000u) | (__float_as_uint(b.z) >> 16);
  return c.v;
}

// ---------------- K0: zero ctx; gather y embedding; convert Wm -> packed bf16 ----------------
__global__ void k0_zero(float* __restrict__ ctx_ws,
                        float* __restrict__ yemb_ws,
                        const int* __restrict__ y, const float* __restrict__ embW,
                        const float* __restrict__ Wm, u16* __restrict__ wmbf){
  int i = blockIdx.x * 256 + threadIdx.x;
  if (i < B_ * M_) { ctx_ws[i] = 0.f; return; }
  i -= B_ * M_;
  if (i < B_ * E_) {
    int b = i >> 7, e = i & 127;
    yemb_ws[i] = embW[(size_t)y[b] * E_ + e];
    return;
  }
  i -= B_ * E_;
  if (i < (H_ * M_) / 8) {
    int j16 = i >> 10;          // 32 col-blocks of 16
    int rem = i & 1023;
    int ks  = rem >> 6;         // 16 K-steps of 32
    int l   = rem & 63;         // lane
    int row = j16 * 16 + (l & 15);
    int col = ks * 32 + (l >> 4) * 8;
    *(bf16x8*)(wmbf + (size_t)i * 8) = pack8(Wm + (size_t)row * 512 + col);
  }
}

// ---------------- K1a: GRU step, weight-stationary, 8-wave K-split ----------------
__global__ __launch_bounds__(512) void k1a_gru(
    const float* __restrict__ h, const float* __restrict__ yemb_ws,
    const float* __restrict__ Wih, const float* __restrict__ Whh,
    const float* __restrict__ bih, const float* __restrict__ bhh,
    float* __restrict__ h1_ws, float* __restrict__ h_out)
{
  __shared__ float red_r[8][64], red_z[8][64], red_nh[8][64], red_ni[8][64];
  int hh = blockIdx.x;
  int t = threadIdx.x, w = t >> 6, lane = t & 63;   // lane = b
  const float* xrow = h + lane * H_;
  const float* erow = yemb_ws + lane * E_;
  const float* wr = Whh + (size_t)hh * H_;
  const float* wz = Whh + (size_t)(hh + H_) * H_;
  const float* wn = Whh + (size_t)(hh + 2 * H_) * H_;
  float pr = 0.f, pz = 0.f, pnh = 0.f, pni = 0.f;
  int k0 = w * 64;
  #pragma unroll
  for (int k = k0; k < k0 + 64; k += 4){
    float4 x = *(const float4*)(xrow + k);
    float4 a = *(const float4*)(wr + k);
    float4 bq = *(const float4*)(wz + k);
    float4 c = *(const float4*)(wn + k);
    pr  += a.x*x.x + a.y*x.y + a.z*x.z + a.w*x.w;
    pz  += bq.x*x.x + bq.y*x.y + bq.z*x.z + bq.w*x.w;
    pnh += c.x*x.x + c.y*x.y + c.z*x.z + c.w*x.w;
  }
  const float* ur = Wih + (size_t)hh * E_;
  const float* uz = Wih + (size_t)(hh + H_) * E_;
  const float* un = Wih + (size_t)(hh + 2 * H_) * E_;
  int e0 = w * 16;
  #pragma unroll
  for (int k = e0; k < e0 + 16; k += 4){
    float4 x = *(const float4*)(erow + k);
    float4 a = *(const float4*)(ur + k);
    float4 bq = *(const float4*)(uz + k);
    float4 c = *(const float4*)(un + k);
    pr  += a.x*x.x + a.y*x.y + a.z*x.z + a.w*x.w;
    pz  += bq.x*x.x + bq.y*x.y + bq.z*x.z + bq.w*x.w;
    pni += c.x*x.x + c.y*x.y + c.z*x.z + c.w*x.w;
  }
  red_r[w][lane] = pr; red_z[w][lane] = pz;
  red_nh[w][lane] = pnh; red_ni[w][lane] = pni;
  __syncthreads();
  if (t < 64){
    int b = t;
    float rr = bih[hh] + bhh[hh];
    float zz = bih[H_ + hh] + bhh[H_ + hh];
    float nh = bhh[2 * H_ + hh];
    float ni = bih[2 * H_ + hh];
    #pragma unroll
    for (int ww = 0; ww < 8; ww++){
      rr += red_r[ww][b]; zz += red_z[ww][b];
      nh += red_nh[ww][b]; ni += red_ni[ww][b];
    }
    float r = sigm(rr), z = sigm(zz);
    float n = fast_tanh(ni + r * nh);
    float h0v = h[b * H_ + hh];
    float h1v = (1.0f - z) * n + z * h0v;
    h1_ws[b * H_ + hh] = h1v;
    h_out[b * H_ + hh] = h1v;
  }
}

// ---------------- K1b: dec_feat = h1 @ Wd^T + bd, 8-wave K-split ----------------
__global__ __launch_bounds__(512) void k1b_dec(
    const float* __restrict__ h1_ws, const float* __restrict__ Wd,
    const float* __restrict__ bd, float* __restrict__ dec_ws)
{
  __shared__ float red[8][64];
  int hh = blockIdx.x;
  int t = threadIdx.x, w = t >> 6, lane = t & 63;
  const float* xrow = h1_ws + lane * H_;
  const float* wd = Wd + (size_t)hh * H_;
  float p = 0.f;
  int k0 = w * 64;
  #pragma unroll
  for (int k = k0; k < k0 + 64; k += 4){
    float4 x = *(const float4*)(xrow + k);
    float4 a = *(const float4*)(wd + k);
    p += a.x*x.x + a.y*x.y + a.z*x.z + a.w*x.w;
  }
  red[w][lane] = p;
  __syncthreads();
  if (t < 64){
    float s = bd[hh];
    #pragma unroll
    for (int ww = 0; ww < 8; ww++) s += red[ww][t];
    dec_ws[t * H_ + hh] = s;
  }
}

// ---------------- K2: MFMA enc GEMM fused with tanh()*v score reduce ----------------
// 400 blocks x 64-row tiles; 8 waves, wave w owns cols w*64..+63 (r4-verified geometry).
// A staged -> swizzled bf16 LDS (dbuf); B packed fragment-order (1KB coalesced, reg-dbuf).
// Halves per-chip packed-B L2 traffic vs 32-row tiles (each block reads all of wm_bf once).
__global__ __launch_bounds__(512) void k2_scores(
    const float* __restrict__ mb, const u16* __restrict__ wmbf,
    const float* __restrict__ dec, const float* __restrict__ cov,
    const float* __restrict__ Wc, const float* __restrict__ av,
    float* __restrict__ scores)
{
  __shared__ u16 alds[2][64 * 128];   // 32 KB, 16B-slot XOR-swizzled by row&7
  __shared__ float sc_lds[64];
  int t = threadIdx.x;
  int lane = t & 63, w = t >> 6;       // 8 waves
  int quad = lane >> 4, l16 = lane & 15;
  int rowB = blockIdx.x * 64;
  int cb = w * 64;
  f32x4 acc[4][4];
  #pragma unroll
  for (int rg = 0; rg < 4; rg++)
    #pragma unroll
    for (int j = 0; j < 4; j++) acc[rg][j] = (f32x4){0.f,0.f,0.f,0.f};

  if (t < 64) sc_lds[t] = 0.f;

  int srow = t >> 4, sg8 = t & 15;                 // staging: rows srow, srow+32
  int sw0 = srow * 128 + 8 * (sg8 ^ (srow & 7));
  int sw1 = (srow + 32) * 128 + 8 * (sg8 ^ (srow & 7));   // (srow+32)&7 == srow&7
  {
    const float* g0 = mb + (size_t)(rowB + srow) * 512 + sg8 * 8;
    float4 a0 = *(const float4*)g0, b0 = *(const float4*)(g0 + 4);
    const float* g1 = g0 + 32 * 512;
    float4 a1 = *(const float4*)g1, b1 = *(const float4*)(g1 + 4);
    *(bf16x8*)&alds[0][sw0] = pack8r(a0, b0);
    *(bf16x8*)&alds[0][sw1] = pack8r(a1, b1);
  }
  // packed B: frag (j, kstep) at wmbf + ((w*4+j)*16 + kstep)*512 + lane*8 (u16 units)
  const u16* wlane = wmbf + lane * 8;
  bf16x8 bcur[4];
  #pragma unroll
  for (int j = 0; j < 4; j++)
    bcur[j] = *(const bf16x8*)(wlane + (size_t)((w * 4 + j) * 16) * 512);
  __syncthreads();
  for (int c = 0; c < 4; c++){
    float4 pa0, pb0, pa1, pb1;
    if (c < 3){
      const float* g0 = mb + (size_t)(rowB + srow) * 512 + (c + 1) * 128 + sg8 * 8;
      pa0 = *(const float4*)g0; pb0 = *(const float4*)(g0 + 4);
      const float* g1 = g0 + 32 * 512;
      pa1 = *(const float4*)g1; pb1 = *(const float4*)(g1 + 4);
    }
    const u16* buf = alds[c & 1];
    #pragma unroll
    for (int s = 0; s < 4; s++){
      bf16x8 bnxt[4];
      bool more = (s < 3) || (c < 3);
      if (more){
        int kn = c * 4 + s + 1;     // next K-step (1..15)
        #pragma unroll
        for (int j = 0; j < 4; j++)
          bnxt[j] = *(const bf16x8*)(wlane + (size_t)((w * 4 + j) * 16 + kn) * 512);
      }
      bf16x8 af[4];
      #pragma unroll
      for (int rg = 0; rg < 4; rg++)
        af[rg] = *(const bf16x8*)&buf[(rg * 16 + l16) * 128 + 8 * ((s * 4 + quad) ^ (l16 & 7))];
      #pragma unroll
      for (int j = 0; j < 4; j++)
        #pragma unroll
        for (int rg = 0; rg < 4; rg++)
          acc[rg][j] = __builtin_amdgcn_mfma_f32_16x16x32_bf16(af[rg], bcur[j], acc[rg][j], 0, 0, 0);
      if (more){
        #pragma unroll
        for (int j = 0; j < 4; j++) bcur[j] = bnxt[j];
      }
    }
    if (c < 3){
      u16* d = (u16*)alds[(c + 1) & 1];
      *(bf16x8*)&d[sw0] = pack8r(pa0, pb0);
      *(bf16x8*)&d[sw1] = pack8r(pa1, pb1);
    }
    __syncthreads();
  }
  float vv[4], wcv[4];
  #pragma unroll
  for (int j = 0; j < 4; j++){
    int hc = cb + j * 16 + l16;
    vv[j] = av[hc]; wcv[j] = Wc[hc];
  }
  #pragma unroll
  for (int rg = 0; rg < 4; rg++){
    #pragma unroll
    for (int r = 0; r < 4; r++){
      int R = rowB + rg * 16 + quad * 4 + r;   // C/D: row = quad*4 + reg
      int bb = R / S_;
      float cf = cov[R];
      const float* decb = dec + bb * H_;
      float sum = 0.f;
      #pragma unroll
      for (int j = 0; j < 4; j++){
        int hc = cb + j * 16 + l16;            // C/D: col = lane&15
        float e = acc[rg][j][r] + decb[hc] + cf * wcv[j];
        sum += fast_tanh(e) * vv[j];
      }
      #pragma unroll
      for (int m = 1; m < 16; m <<= 1) sum += __shfl_xor(sum, m, 64);
      if (l16 == 0) atomicAdd(&sc_lds[R - rowB], sum);
    }
  }
  __syncthreads();
  if (t < 64) scores[rowB + t] = sc_lds[t];
}

// ---------------- K3a: masked softmax + renorm; attn + coverage_next outputs ----------------
__global__ __launch_bounds__(256) void k3a_softmax(
    const float* __restrict__ scores, const float* __restrict__ mask,
    const float* __restrict__ cov,
    float* __restrict__ attn_ws,
    float* __restrict__ out_attn, float* __restrict__ out_cov)
{
  __shared__ float p_s[S_];
  __shared__ float m_s[S_];
  __shared__ float red[256];
  int b = blockIdx.x, t = threadIdx.x;
  float lmax = -3.0e38f;
  for (int s = t; s < S_; s += 256){
    float mk = mask[b*S_ + s];
    float v = scores[b*S_ + s];
    v = (mk > 0.f) ? v : -1e9f;
    p_s[s] = v; m_s[s] = mk;
    lmax = fmaxf(lmax, v);
  }
  red[t] = lmax; __syncthreads();
  for (int o = 128; o > 0; o >>= 1){ if (t < o) red[t] = fmaxf(red[t], red[t+o]); __syncthreads(); }
  float MX = red[0]; __syncthreads();
  float lsum = 0.f;
  for (int s = t; s < S_; s += 256){ float e = __expf(p_s[s] - MX); p_s[s] = e; lsum += e; }
  red[t] = lsum; __syncthreads();
  for (int o = 128; o > 0; o >>= 1){ if (t < o) red[t] += red[t+o]; __syncthreads(); }
  float inv1 = 1.0f / red[0]; __syncthreads();
  float l2 = 0.f;
  for (int s = t; s < S_; s += 256){ float a = p_s[s] * inv1 * m_s[s]; p_s[s] = a; l2 += a; }
  red[t] = l2; __syncthreads();
  for (int o = 128; o > 0; o >>= 1){ if (t < o) red[t] += red[t+o]; __syncthreads(); }
  float inv2 = 1.0f / (red[0] + 1e-10f); __syncthreads();
  for (int s = t; s < S_; s += 256){
    float a = p_s[s] * inv2;
    attn_ws[b*S_ + s] = a;
    out_attn[b*S_ + s] = a;
    out_cov[b*S_ + s]  = cov[b*S_ + s] + a;
  }
}

// ---------------- K3b: word_context GEMV: ctx[b,m] += sum_s attn[b,s]*mb[b,s,m] ----------------
__global__ __launch_bounds__(256) void k3b_ctx(
    const float* __restrict__ attn_ws, const float* __restrict__ mb,
    float* __restrict__ ctx_ws)
{
  int b = blockIdx.x, sc = blockIdx.y, t = threadIdx.x;
  int m0 = t * 2;
  const float* mbb = mb + (size_t)b * S_ * M_;
  const float* ab  = attn_ws + b * S_;
  float a0 = 0.f, a1 = 0.f;
  int s0 = sc * 25;
  for (int s = s0; s < s0 + 25; s++){
    float a = ab[s];
    float2 c = *(const float2*)(mbb + s*M_ + m0);
    a0 += a * c.x;
    a1 += a * c.y;
  }
  atomicAdd(&ctx_ws[b*M_ + m0],     a0);
  atomicAdd(&ctx_ws[b*M_ + m0 + 1], a1);
}

// ---------------- K4a: hid = [ctx,h1].vd1W[hh,:]+b, weight-stationary; PACKED hid output ----------------
__global__ __launch_bounds__(512) void k4a_hid(
    const float* __restrict__ ctx_ws, const float* __restrict__ h1_ws,
    const float* __restrict__ vd1W, const float* __restrict__ vd1b,
    u16* __restrict__ hid_pk, float* __restrict__ out_ctx)
{
  __shared__ float red[8][64];
  int hh = blockIdx.x;
  int t = threadIdx.x, w = t >> 6, lane = t & 63;   // lane = b
  int k0 = w * 128;
  const float* xbase = (w < 4) ? (ctx_ws + lane * 512 + k0)
                               : (h1_ws + lane * 512 + (k0 - 512));
  const float* wrow = vd1W + (size_t)hh * 1024 + k0;
  float p = 0.f;
  #pragma unroll 8
  for (int k = 0; k < 128; k += 4){
    float4 x = *(const float4*)(xbase + k);
    float4 a = *(const float4*)(wrow + k);
    p += a.x*x.x + a.y*x.y + a.z*x.z + a.w*x.w;
  }
  red[w][lane] = p;
  __syncthreads();
  if (t < 64){
    float s = vd1b[hh];
    #pragma unroll
    for (int ww = 0; ww < 8; ww++) s += red[ww][t];
    // packed index: row = t, col = hh
    int ks = hh >> 5, rg = t >> 4;
    int ln = (t & 15) + (((hh >> 3) & 3) << 4);
    int e  = hh & 7;
    hid_pk[(size_t)((ks * 4 + rg) * 64 + ln) * 8 + e] = f2b(s);
    out_ctx[t * 512 + hh] = ctx_ws[t * 512 + hh];
  }
}

// ---------------- K4b: p_gen only ----------------
__global__ __launch_bounds__(128) void k4b_pgen(
    const float* __restrict__ ctx_ws, const float* __restrict__ h1_ws,
    const float* __restrict__ yemb_ws,
    const float* __restrict__ pgW, const float* __restrict__ pgb,
    float* __restrict__ pgen_ws, float* __restrict__ out_pgen)
{
  __shared__ float red[128];
  int b = blockIdx.x, t = threadIdx.x;
  float p = 0.f;
  for (int i = t; i < 1152; i += 128){
    float x = (i < 512) ? ctx_ws[b * 512 + i]
            : (i < 1024) ? h1_ws[b * 512 + (i - 512)]
                         : yemb_ws[b * 128 + (i - 1024)];
    p += x * pgW[i];
  }
  red[t] = p; __syncthreads();
  for (int o = 64; o > 0; o >>= 1){ if (t < o) red[t] += red[t + o]; __syncthreads(); }
  if (t == 0){
    float pg = sigm(red[0] + pgb[0]);
    pgen_ws[b] = pg; out_pgen[b] = pg;
  }
}

// ---------------- K5: MFMA logits GEMM: [64,V] = hid[64,512] . vd2W[V,512]^T ----------------
// A from PACKED hid (1KB contiguous wave loads, L2-resident); B staged -> swizzled LDS dbuf.
__global__ __launch_bounds__(256) void k5_logits(
    const u16* __restrict__ hid_pk, const float* __restrict__ vd2W,
    const float* __restrict__ vd2b, int V, u16* __restrict__ logits_bf)
{
  __shared__ u16 blds[2][64 * 128];   // 32 KB
  int t = threadIdx.x;
  int lane = t & 63, w = t >> 6;
  int quad = lane >> 4, l16 = lane & 15;
  int cb = blockIdx.x * 64;
  f32x4 acc[4];
  #pragma unroll
  for (int rg = 0; rg < 4; rg++) acc[rg] = (f32x4){0.f,0.f,0.f,0.f};

  // staging map: 1024 groups (64 cols x 16 g8); thread handles 4 groups
  int scol0 = t >> 4, sg8 = t & 15;
  {
    #pragma unroll
    for (int i = 0; i < 4; i++){
      int col = scol0 + i * 16;
      int gr = cb + col; if (gr > V - 1) gr = V - 1;
      const float* gs = vd2W + (size_t)gr * 512 + sg8 * 8;
      float4 x = *(const float4*)gs, yv = *(const float4*)(gs + 4);
      *(bf16x8*)&blds[0][col * 128 + 8 * (sg8 ^ (col & 7))] = pack8r(x, yv);
    }
  }
  const u16* hlane = hid_pk + lane * 8;
  __syncthreads();
  int cw = w * 16 + l16;
  for (int c = 0; c < 4; c++){
    float4 px0, py0, px1, py1, px2, py2, px3, py3;
    if (c < 3){
      int kc = (c + 1) * 128;
      int g0 = cb + scol0;      if (g0 > V-1) g0 = V-1;
      int g1 = cb + scol0 + 16; if (g1 > V-1) g1 = V-1;
      int g2 = cb + scol0 + 32; if (g2 > V-1) g2 = V-1;
      int g3 = cb + scol0 + 48; if (g3 > V-1) g3 = V-1;
      const float* s0 = vd2W + (size_t)g0 * 512 + kc + sg8 * 8;
      const float* s1 = vd2W + (size_t)g1 * 512 + kc + sg8 * 8;
      const float* s2 = vd2W + (size_t)g2 * 512 + kc + sg8 * 8;
      const float* s3 = vd2W + (size_t)g3 * 512 + kc + sg8 * 8;
      px0 = *(const float4*)s0; py0 = *(const float4*)(s0 + 4);
      px1 = *(const float4*)s1; py1 = *(const float4*)(s1 + 4);
      px2 = *(const float4*)s2; py2 = *(const float4*)(s2 + 4);
      px3 = *(const float4*)s3; py3 = *(const float4*)(s3 + 4);
    }
    // batch-load all 16 A-frags for this chunk: packed, 1KB contiguous per frag
    bf16x8 aF[4][4];
    #pragma unroll
    for (int s = 0; s < 4; s++)
      #pragma unroll
      for (int rg = 0; rg < 4; rg++)
        aF[s][rg] = *(const bf16x8*)(hlane + (size_t)((c * 4 + s) * 4 + rg) * 512);
    const u16* buf = blds[c & 1];
    #pragma unroll
    for (int s = 0; s < 4; s++){
      bf16x8 bfb = *(const bf16x8*)&buf[cw * 128 + 8 * ((s * 4 + quad) ^ (cw & 7))];
      #pragma unroll
      for (int rg = 0; rg < 4; rg++)
        acc[rg] = __builtin_amdgcn_mfma_f32_16x16x32_bf16(aF[s][rg], bfb, acc[rg], 0, 0, 0);
    }
    if (c < 3){
      u16* d = (u16*)blds[(c + 1) & 1];
      *(bf16x8*)&d[scol0 * 128        + 8 * (sg8 ^ (scol0 & 7))]        = pack8r(px0, py0);
      *(bf16x8*)&d[(scol0+16) * 128   + 8 * (sg8 ^ ((scol0+16) & 7))]   = pack8r(px1, py1);
      *(bf16x8*)&d[(scol0+32) * 128   + 8 * (sg8 ^ ((scol0+32) & 7))]   = pack8r(px2, py2);
      *(bf16x8*)&d[(scol0+48) * 128   + 8 * (sg8 ^ ((scol0+48) & 7))]   = pack8r(px3, py3);
    }
    __syncthreads();
  }
  int v = cb + w * 16 + l16;
  if (v < V){
    float bias = vd2b[v];
    #pragma unroll
    for (int rg = 0; rg < 4; rg++){
      #pragma unroll
      for (int r = 0; r < 4; r++){
        int bb = rg * 16 + quad * 4 + r;
        logits_bf[(size_t)bb * V + v] = f2b(acc[rg][r] + bias);
      }
    }
  }
}

// ---------------- K6a: per-(b,chunk) max & partial sum(exp), vectorized ----------------
__global__ __launch_bounds__(256) void k6a_partial(
    const u16* __restrict__ logits_bf, int V,
    float* __restrict__ mxp, float* __restrict__ denp)
{
  __shared__ float red[256];
  int b = blockIdx.x, ch = blockIdx.y, t = threadIdx.x;
  int VG = V >> 3;                     // groups of 8 (V % 8 == 0)
  int per = (VG + 7) >> 3;             // groups per chunk (8 chunks)
  int g0 = ch * per;
  int g1 = g0 + per; if (g1 > VG) g1 = VG;
  const bf16x8* row = (const bf16x8*)(logits_bf + (size_t)b * V);
  float x[32];
  float m = -3.0e38f;
  #pragma unroll
  for (int i = 0; i < 4; i++){
    int g = g0 + t + i * 256;
    bool ok = g < g1;
    bf16x8 v;
    if (ok) v = row[g];
    #pragma unroll
    for (int j = 0; j < 8; j++){
      float f = ok ? b2f((u16)v[j]) : -3.0e38f;
      x[i * 8 + j] = f;
      m = fmaxf(m, f);
    }
  }
  red[t] = m; __syncthreads();
  for (int o = 128; o > 0; o >>= 1){ if (t < o) red[t] = fmaxf(red[t], red[t+o]); __syncthreads(); }
  float MX = red[0]; __syncthreads();
  float s = 0.f;
  #pragma unroll
  for (int k = 0; k < 32; k++) s += __expf(x[k] - MX);
  red[t] = s; __syncthreads();
  for (int o = 128; o > 0; o >>= 1){ if (t < o) red[t] += red[t+o]; __syncthreads(); }
  if (t == 0){ mxp[b * 8 + ch] = MX; denp[b * 8 + ch] = red[0]; }
}

// ---------------- K7a: out_final = p_gen * softmax(logits); combine folded in ----------------
__global__ void k7a_vocab(const u16* __restrict__ logits_bf,
    const float* __restrict__ mxp, const float* __restrict__ denp,
    const float* __restrict__ pgen_ws, int V, int VO, float* __restrict__ out_final)
{
  int b = blockIdx.y;
  // per-block recompute of the 8-partial combine (wave-uniform scalar loads)
  float MX = -3.0e38f;
  #pragma unroll
  for (int cix = 0; cix < 8; cix++) MX = fmaxf(MX, mxp[b * 8 + cix]);
  float den = 0.f;
  #pragma unroll
  for (int cix = 0; cix < 8; cix++) den += denp[b * 8 + cix] * __expf(mxp[b * 8 + cix] - MX);
  int c = (blockIdx.x * 256 + threadIdx.x) * 4;
  if (c >= VO) return;
  float inv = pgen_ws[b] / den;
  float v4[4] = {0.f, 0.f, 0.f, 0.f};
  if (c + 3 < V){
    ushort4 u = *(const ushort4*)(logits_bf + (size_t)b * V + c);
    v4[0] = inv * __expf(b2f(u.x) - MX);
    v4[1] = inv * __expf(b2f(u.y) - MX);
    v4[2] = inv * __expf(b2f(u.z) - MX);
    v4[3] = inv * __expf(b2f(u.w) - MX);
  } else {
    #pragma unroll
    for (int j = 0; j < 4; j++){
      int cc = c + j;
      if (cc < V) v4[j] = inv * __expf(b2f(logits_bf[(size_t)b * V + cc]) - MX);
    }
  }
  if (c + 4 <= VO){
    *(float4*)(out_final + (size_t)b * VO + c) = make_float4(v4[0], v4[1], v4[2], v4[3]);
  } else {
    for (int j = 0; j < 4 && c + j < VO; j++) out_final[(size_t)b * VO + c + j] = v4[j];
  }
}

// ---------------- K7b: scatter-add (1-p_gen)*attn at src_oov (fp32 atomic) ----------------
__global__ void k7b_scatter(const int* __restrict__ src_oov,
    const float* __restrict__ attn_ws, const float* __restrict__ pgen_ws,
    int VO, float* __restrict__ out_final)
{
  int idx = blockIdx.x * 256 + threadIdx.x;
  if (idx >= R_) return;
  int b = idx / S_;
  float ad = (1.0f - pgen_ws[b]) * attn_ws[idx];
  atomicAdd(&out_final[(size_t)b*VO + src_oov[idx]], ad);
}

extern "C" void kernel_launch(void* const* d_in, const int* in_sizes, int n_in,
                              void* d_out, int out_size, void* d_ws, size_t ws_size,
                              hipStream_t stream)
{
  const int*   y      = (const int*)d_in[0];
  const float* h      = (const float*)d_in[1];
  const float* mb     = (const float*)d_in[2];
  const float* mask   = (const float*)d_in[3];
  const int*   srcoov = (const int*)d_in[5];
  const float* cov    = (const float*)d_in[6];
  const float* embW   = (const float*)d_in[7];
  const float* Wih    = (const float*)d_in[8];
  const float* Whh    = (const float*)d_in[9];
  const float* bih    = (const float*)d_in[10];
  const float* bhh    = (const float*)d_in[11];
  const float* Wm     = (const float*)d_in[12];
  const float* Wd     = (const float*)d_in[13];
  const float* bd     = (const float*)d_in[14];
  const float* Wc     = (const float*)d_in[15];
  const float* av     = (const float*)d_in[16];
  const float* pgW    = (const float*)d_in[17];
  const float* pgb    = (const float*)d_in[18];
  const float* vd1W   = (const float*)d_in[19];
  const float* vd1b   = (const float*)d_in[20];
  const float* vd2W   = (const float*)d_in[21];
  const float* vd2b   = (const float*)d_in[22];

  // dynamic dims: V from vd2_b size; VO from out_size (fp32 elements):
  // out_size = B*(VO + H + M + 2S + 1)
  const int V  = in_sizes[22];
  const int VO = (int)((long long)out_size / B_ - (H_ + M_ + 2*S_ + 1));

  float* out = (float*)d_out;
  float* out_final = out;                                 // [B, VO]
  float* out_h     = out_final + (size_t)B_ * VO;         // [1,B,H]
  float* out_ctx   = out_h     + (size_t)B_ * H_;         // [B,M]
  float* out_attn  = out_ctx   + (size_t)B_ * M_;         // [B,S]
  float* out_pgen  = out_attn  + (size_t)B_ * S_;         // [B,1]
  float* out_cov   = out_pgen  + B_;                      // [B,S]

  float* ws      = (float*)d_ws;
  float* scores  = ws;                        // 25600 (dead after k3a; reused by k6 partials)
  float* h1_ws   = ws + 25600;                // 32768
  float* yemb_ws = ws + 58368;                // 8192
  float* dec_ws  = ws + 66560;                // 32768
  float* attn_ws = ws + 99328;                // 25600
  float* ctx_ws  = ws + 124928;               // 32768
  float* pgen_ws = ws + 157696;               // 64
  u16*   hid_pk    = (u16*)(ws + 157888);     // 32768 u16 (packed A-frags for k5)
  u16*   logits_bf = (u16*)(ws + 174272);     // B*V u16 (~6.4 MB)
  // wm_bf aliases the head of logits_bf: wm_bf is written by k0 and dead after
  // k2; logits_bf is first written by k5 (stream-ordered after k2).
  u16*   wm_bf     = logits_bf;               // 262144 u16 (512 KB)
  // k6 partials alias dead scores region (scores read last by k3a)
  float* mxp_ws  = scores;                    // 512
  float* denp_ws = scores + 512;              // 512

  hipLaunchKernelGGL(k0_zero,    dim3(288),  dim3(256), 0, stream,
                     ctx_ws, yemb_ws, y, embW, Wm, wm_bf);
  hipLaunchKernelGGL(k1a_gru,    dim3(512),  dim3(512), 0, stream,
                     h, yemb_ws, Wih, Whh, bih, bhh, h1_ws, out_h);
  hipLaunchKernelGGL(k1b_dec,    dim3(512),  dim3(512), 0, stream,
                     h1_ws, Wd, bd, dec_ws);
  hipLaunchKernelGGL(k2_scores,  dim3(400),  dim3(512), 0, stream,
                     mb, wm_bf, dec_ws, cov, Wc, av, scores);
  hipLaunchKernelGGL(k3a_softmax, dim3(64),  dim3(256), 0, stream,
                     scores, mask, cov, attn_ws, out_attn, out_cov);
  hipLaunchKernelGGL(k3b_ctx,    dim3(64, 16), dim3(256), 0, stream,
                     attn_ws, mb, ctx_ws);
  hipLaunchKernelGGL(k4a_hid,    dim3(512),  dim3(512), 0, stream,
                     ctx_ws, h1_ws, vd1W, vd1b, hid_pk, out_ctx);
  hipLaunchKernelGGL(k4b_pgen,   dim3(64),   dim3(128), 0, stream,
                     ctx_ws, h1_ws, yemb_ws, pgW, pgb, pgen_ws, out_pgen);
  hipLaunchKernelGGL(k5_logits,  dim3((V + 63) / 64), dim3(256), 0, stream,
                     hid_pk, vd2W, vd2b, V, logits_bf);
  hipLaunchKernelGGL(k6a_partial, dim3(64, 8), dim3(256), 0, stream,
                     logits_bf, V, mxp_ws, denp_ws);
  hipLaunchKernelGGL(k7a_vocab,  dim3((VO + 1023) / 1024, 64), dim3(256), 0, stream,
                     logits_bf, mxp_ws, denp_ws, pgen_ws, V, VO, out_final);
  hipLaunchKernelGGL(k7b_scatter, dim3(100), dim3(256), 0, stream,
                     srcoov, attn_ws, pgen_ws, VO, out_final);
}

// Round 11
// 377.610 us; speedup vs baseline: 1.0265x; 1.0265x over previous
//
#include <hip/hip_runtime.h>

typedef unsigned short u16;
typedef unsigned int u32;
using bf16x8 = __attribute__((ext_vector_type(8))) short;
using f32x4  = __attribute__((ext_vector_type(4))) float;

#define B_ 64
#define S_ 400
#define E_ 128
#define H_ 512
#define M_ 512
#define R_ (B_ * S_)   // 25600

__device__ __forceinline__ float b2f(u16 u){
  union { u32 i; float f; } c; c.i = ((u32)u) << 16; return c.f;
}
__device__ __forceinline__ u16 f2b(float f){
  union { u32 i; float f; } c; c.f = f;
  u32 r = c.i + 0x7FFFu + ((c.i >> 16) & 1u);
  return (u16)(r >> 16);
}
__device__ __forceinline__ float sigm(float x){ return 1.0f / (1.0f + __expf(-x)); }
__device__ __forceinline__ float fast_tanh(float x){
  float e = __expf(2.0f * x);
  return 1.0f - 2.0f / (e + 1.0f);
}
// pack 8 consecutive fp32 -> bf16x8 (truncate: take high u16 of each fp32)
__device__ __forceinline__ bf16x8 pack8(const float* __restrict__ p){
  const u32* u = (const u32*)p;
  union { u32 w[4]; bf16x8 v; } c;
  c.w[0] = (u[1] & 0xFFFF0000u) | (u[0] >> 16);
  c.w[1] = (u[3] & 0xFFFF0000u) | (u[2] >> 16);
  c.w[2] = (u[5] & 0xFFFF0000u) | (u[4] >> 16);
  c.w[3] = (u[7] & 0xFFFF0000u) | (u[6] >> 16);
  return c.v;
}
// pack two float4 (8 consecutive fp32) -> bf16x8, same truncation as pack8
__device__ __forceinline__ bf16x8 pack8r(float4 a, float4 b){
  union { u32 w[4]; bf16x8 v; } c;
  c.w[0] = (__float_as_uint(a.y) & 0xFFFF0000u) | (__float_as_uint(a.x) >> 16);
  c.w[1] = (__float_as_uint(a.w) & 0xFFFF0000u) | (__float_as_uint(a.z) >> 16);
  c.w[2] = (__float_as_uint(b.y) & 0xFFFF0000u) | (__float_as_uint(b.x) >> 16);
  c.w[3] = (__float_as_uint(b.w) & 0xFFFF0000u) | (__float_as_uint(b.z) >> 16);
  return c.v;
}

// ---------------- K0: zero ctx; gather y embedding; convert Wm -> packed bf16 ----------------
__global__ void k0_zero(float* __restrict__ ctx_ws,
                        float* __restrict__ yemb_ws,
                        const int* __restrict__ y, const float* __restrict__ embW,
                        const float* __restrict__ Wm, u16* __restrict__ wmbf){
  int i = blockIdx.x * 256 + threadIdx.x;
  if (i < B_ * M_) { ctx_ws[i] = 0.f; return; }
  i -= B_ * M_;
  if (i < B_ * E_) {
    int b = i >> 7, e = i & 127;
    yemb_ws[i] = embW[(size_t)y[b] * E_ + e];
    return;
  }
  i -= B_ * E_;
  if (i < (H_ * M_) / 8) {
    int j16 = i >> 10;          // 32 col-blocks of 16
    int rem = i & 1023;
    int ks  = rem >> 6;         // 16 K-steps of 32
    int l   = rem & 63;         // lane
    int row = j16 * 16 + (l & 15);
    int col = ks * 32 + (l >> 4) * 8;
    *(bf16x8*)(wmbf + (size_t)i * 8) = pack8(Wm + (size_t)row * 512 + col);
  }
}

// ---------------- K1a: GRU step, weight-stationary, 8-wave K-split ----------------
__global__ __launch_bounds__(512) void k1a_gru(
    const float* __restrict__ h, const float* __restrict__ yemb_ws,
    const float* __restrict__ Wih, const float* __restrict__ Whh,
    const float* __restrict__ bih, const float* __restrict__ bhh,
    float* __restrict__ h1_ws, float* __restrict__ h_out)
{
  __shared__ float red_r[8][64], red_z[8][64], red_nh[8][64], red_ni[8][64];
  int hh = blockIdx.x;
  int t = threadIdx.x, w = t >> 6, lane = t & 63;   // lane = b
  const float* xrow = h + lane * H_;
  const float* erow = yemb_ws + lane * E_;
  const float* wr = Whh + (size_t)hh * H_;
  const float* wz = Whh + (size_t)(hh + H_) * H_;
  const float* wn = Whh + (size_t)(hh + 2 * H_) * H_;
  float pr = 0.f, pz = 0.f, pnh = 0.f, pni = 0.f;
  int k0 = w * 64;
  #pragma unroll
  for (int k = k0; k < k0 + 64; k += 4){
    float4 x = *(const float4*)(xrow + k);
    float4 a = *(const float4*)(wr + k);
    float4 bq = *(const float4*)(wz + k);
    float4 c = *(const float4*)(wn + k);
    pr  += a.x*x.x + a.y*x.y + a.z*x.z + a.w*x.w;
    pz  += bq.x*x.x + bq.y*x.y + bq.z*x.z + bq.w*x.w;
    pnh += c.x*x.x + c.y*x.y + c.z*x.z + c.w*x.w;
  }
  const float* ur = Wih + (size_t)hh * E_;
  const float* uz = Wih + (size_t)(hh + H_) * E_;
  const float* un = Wih + (size_t)(hh + 2 * H_) * E_;
  int e0 = w * 16;
  #pragma unroll
  for (int k = e0; k < e0 + 16; k += 4){
    float4 x = *(const float4*)(erow + k);
    float4 a = *(const float4*)(ur + k);
    float4 bq = *(const float4*)(uz + k);
    float4 c = *(const float4*)(un + k);
    pr  += a.x*x.x + a.y*x.y + a.z*x.z + a.w*x.w;
    pz  += bq.x*x.x + bq.y*x.y + bq.z*x.z + bq.w*x.w;
    pni += c.x*x.x + c.y*x.y + c.z*x.z + c.w*x.w;
  }
  red_r[w][lane] = pr; red_z[w][lane] = pz;
  red_nh[w][lane] = pnh; red_ni[w][lane] = pni;
  __syncthreads();
  if (t < 64){
    int b = t;
    float rr = bih[hh] + bhh[hh];
    float zz = bih[H_ + hh] + bhh[H_ + hh];
    float nh = bhh[2 * H_ + hh];
    float ni = bih[2 * H_ + hh];
    #pragma unroll
    for (int ww = 0; ww < 8; ww++){
      rr += red_r[ww][b]; zz += red_z[ww][b];
      nh += red_nh[ww][b]; ni += red_ni[ww][b];
    }
    float r = sigm(rr), z = sigm(zz);
    float n = fast_tanh(ni + r * nh);
    float h0v = h[b * H_ + hh];
    float h1v = (1.0f - z) * n + z * h0v;
    h1_ws[b * H_ + hh] = h1v;
    h_out[b * H_ + hh] = h1v;
  }
}

// ---------------- K1b: dec_feat = h1 @ Wd^T + bd, 8-wave K-split ----------------
__global__ __launch_bounds__(512) void k1b_dec(
    const float* __restrict__ h1_ws, const float* __restrict__ Wd,
    const float* __restrict__ bd, float* __restrict__ dec_ws)
{
  __shared__ float red[8][64];
  int hh = blockIdx.x;
  int t = threadIdx.x, w = t >> 6, lane = t & 63;
  const float* xrow = h1_ws + lane * H_;
  const float* wd = Wd + (size_t)hh * H_;
  float p = 0.f;
  int k0 = w * 64;
  #pragma unroll
  for (int k = k0; k < k0 + 64; k += 4){
    float4 x = *(const float4*)(xrow + k);
    float4 a = *(const float4*)(wd + k);
    p += a.x*x.x + a.y*x.y + a.z*x.z + a.w*x.w;
  }
  red[w][lane] = p;
  __syncthreads();
  if (t < 64){
    float s = bd[hh];
    #pragma unroll
    for (int ww = 0; ww < 8; ww++) s += red[ww][t];
    dec_ws[t * H_ + hh] = s;
  }
}

// ---------------- K2: MFMA enc GEMM fused with tanh()*v score reduce ----------------
// 800 blocks x 32-row tiles; 8 waves, wave w owns cols w*64..+63 (round-9 best geometry).
// A staged -> swizzled bf16 LDS (dbuf); B packed fragment-order (coalesced, reg-dbuf).
// Scores: per-block LDS reduce + direct store (block owns its rows fully).
__global__ __launch_bounds__(512) void k2_scores(
    const float* __restrict__ mb, const u16* __restrict__ wmbf,
    const float* __restrict__ dec, const float* __restrict__ cov,
    const float* __restrict__ Wc, const float* __restrict__ av,
    float* __restrict__ scores)
{
  __shared__ u16 alds[2][32 * 128];   // 16 KB, 16B-slot XOR-swizzled by row&7
  __shared__ float sc_lds[32];
  int t = threadIdx.x;
  int lane = t & 63, w = t >> 6;       // 8 waves
  int quad = lane >> 4, l16 = lane & 15;
  int rowB = blockIdx.x * 32;
  int cb = w * 64;
  f32x4 acc[2][4];
  #pragma unroll
  for (int rg = 0; rg < 2; rg++)
    #pragma unroll
    for (int j = 0; j < 4; j++) acc[rg][j] = (f32x4){0.f,0.f,0.f,0.f};

  if (t < 32) sc_lds[t] = 0.f;

  int srow = t >> 4, sg8 = t & 15;                 // staging: 1 row-chunk/thread
  int sw0 = srow * 128 + 8 * (sg8 ^ (srow & 7));
  {
    const float* g0 = mb + (size_t)(rowB + srow) * 512 + sg8 * 8;
    float4 a0 = *(const float4*)g0, b0 = *(const float4*)(g0 + 4);
    *(bf16x8*)&alds[0][sw0] = pack8r(a0, b0);
  }
  // packed B: frag (j, kstep) at wmbf + ((w*4+j)*16 + kstep)*512 + lane*8 (u16 units)
  const u16* wlane = wmbf + lane * 8;
  bf16x8 bcur[4];
  #pragma unroll
  for (int j = 0; j < 4; j++)
    bcur[j] = *(const bf16x8*)(wlane + (size_t)((w * 4 + j) * 16) * 512);
  __syncthreads();
  for (int c = 0; c < 4; c++){
    float4 pa0, pb0;
    if (c < 3){
      const float* g0 = mb + (size_t)(rowB + srow) * 512 + (c + 1) * 128 + sg8 * 8;
      pa0 = *(const float4*)g0; pb0 = *(const float4*)(g0 + 4);
    }
    const u16* buf = alds[c & 1];
    #pragma unroll
    for (int s = 0; s < 4; s++){
      bf16x8 bnxt[4];
      bool more = (s < 3) || (c < 3);
      if (more){
        int kn = c * 4 + s + 1;     // next K-step (1..15)
        #pragma unroll
        for (int j = 0; j < 4; j++)
          bnxt[j] = *(const bf16x8*)(wlane + (size_t)((w * 4 + j) * 16 + kn) * 512);
      }
      bf16x8 af[2];
      #pragma unroll
      for (int rg = 0; rg < 2; rg++)
        af[rg] = *(const bf16x8*)&buf[(rg * 16 + l16) * 128 + 8 * ((s * 4 + quad) ^ (l16 & 7))];
      #pragma unroll
      for (int j = 0; j < 4; j++)
        #pragma unroll
        for (int rg = 0; rg < 2; rg++)
          acc[rg][j] = __builtin_amdgcn_mfma_f32_16x16x32_bf16(af[rg], bcur[j], acc[rg][j], 0, 0, 0);
      if (more){
        #pragma unroll
        for (int j = 0; j < 4; j++) bcur[j] = bnxt[j];
      }
    }
    if (c < 3){
      u16* d = (u16*)alds[(c + 1) & 1];
      *(bf16x8*)&d[sw0] = pack8r(pa0, pb0);
    }
    __syncthreads();
  }
  float vv[4], wcv[4];
  #pragma unroll
  for (int j = 0; j < 4; j++){
    int hc = cb + j * 16 + l16;
    vv[j] = av[hc]; wcv[j] = Wc[hc];
  }
  #pragma unroll
  for (int rg = 0; rg < 2; rg++){
    #pragma unroll
    for (int r = 0; r < 4; r++){
      int R = rowB + rg * 16 + quad * 4 + r;   // C/D: row = quad*4 + reg
      int bb = R / S_;
      float cf = cov[R];
      const float* decb = dec + bb * H_;
      float sum = 0.f;
      #pragma unroll
      for (int j = 0; j < 4; j++){
        int hc = cb + j * 16 + l16;            // C/D: col = lane&15
        float e = acc[rg][j][r] + decb[hc] + cf * wcv[j];
        sum += fast_tanh(e) * vv[j];
      }
      #pragma unroll
      for (int m = 1; m < 16; m <<= 1) sum += __shfl_xor(sum, m, 64);
      if (l16 == 0) atomicAdd(&sc_lds[R - rowB], sum);
    }
  }
  __syncthreads();
  if (t < 32) scores[rowB + t] = sc_lds[t];
}

// ---------------- K3a: masked softmax + renorm; attn + coverage_next outputs ----------------
__global__ __launch_bounds__(256) void k3a_softmax(
    const float* __restrict__ scores, const float* __restrict__ mask,
    const float* __restrict__ cov,
    float* __restrict__ attn_ws,
    float* __restrict__ out_attn, float* __restrict__ out_cov)
{
  __shared__ float p_s[S_];
  __shared__ float m_s[S_];
  __shared__ float red[256];
  int b = blockIdx.x, t = threadIdx.x;
  float lmax = -3.0e38f;
  for (int s = t; s < S_; s += 256){
    float mk = mask[b*S_ + s];
    float v = scores[b*S_ + s];
    v = (mk > 0.f) ? v : -1e9f;
    p_s[s] = v; m_s[s] = mk;
    lmax = fmaxf(lmax, v);
  }
  red[t] = lmax; __syncthreads();
  for (int o = 128; o > 0; o >>= 1){ if (t < o) red[t] = fmaxf(red[t], red[t+o]); __syncthreads(); }
  float MX = red[0]; __syncthreads();
  float lsum = 0.f;
  for (int s = t; s < S_; s += 256){ float e = __expf(p_s[s] - MX); p_s[s] = e; lsum += e; }
  red[t] = lsum; __syncthreads();
  for (int o = 128; o > 0; o >>= 1){ if (t < o) red[t] += red[t+o]; __syncthreads(); }
  float inv1 = 1.0f / red[0]; __syncthreads();
  float l2 = 0.f;
  for (int s = t; s < S_; s += 256){ float a = p_s[s] * inv1 * m_s[s]; p_s[s] = a; l2 += a; }
  red[t] = l2; __syncthreads();
  for (int o = 128; o > 0; o >>= 1){ if (t < o) red[t] += red[t+o]; __syncthreads(); }
  float inv2 = 1.0f / (red[0] + 1e-10f); __syncthreads();
  for (int s = t; s < S_; s += 256){
    float a = p_s[s] * inv2;
    attn_ws[b*S_ + s] = a;
    out_attn[b*S_ + s] = a;
    out_cov[b*S_ + s]  = cov[b*S_ + s] + a;
  }
}

// ---------------- K3b: word_context GEMV: ctx[b,m] += sum_s attn[b,s]*mb[b,s,m] ----------------
__global__ __launch_bounds__(256) void k3b_ctx(
    const float* __restrict__ attn_ws, const float* __restrict__ mb,
    float* __restrict__ ctx_ws)
{
  int b = blockIdx.x, sc = blockIdx.y, t = threadIdx.x;
  int m0 = t * 2;
  const float* mbb = mb + (size_t)b * S_ * M_;
  const float* ab  = attn_ws + b * S_;
  float a0 = 0.f, a1 = 0.f;
  int s0 = sc * 25;
  for (int s = s0; s < s0 + 25; s++){
    float a = ab[s];
    float2 c = *(const float2*)(mbb + s*M_ + m0);
    a0 += a * c.x;
    a1 += a * c.y;
  }
  atomicAdd(&ctx_ws[b*M_ + m0],     a0);
  atomicAdd(&ctx_ws[b*M_ + m0 + 1], a1);
}

// ---------------- K4a: hid = [ctx,h1].vd1W[hh,:]+b, weight-stationary; PACKED hid output ----------------
__global__ __launch_bounds__(512) void k4a_hid(
    const float* __restrict__ ctx_ws, const float* __restrict__ h1_ws,
    const float* __restrict__ vd1W, const float* __restrict__ vd1b,
    u16* __restrict__ hid_pk, float* __restrict__ out_ctx)
{
  __shared__ float red[8][64];
  int hh = blockIdx.x;
  int t = threadIdx.x, w = t >> 6, lane = t & 63;   // lane = b
  int k0 = w * 128;
  const float* xbase = (w < 4) ? (ctx_ws + lane * 512 + k0)
                               : (h1_ws + lane * 512 + (k0 - 512));
  const float* wrow = vd1W + (size_t)hh * 1024 + k0;
  float p = 0.f;
  #pragma unroll 8
  for (int k = 0; k < 128; k += 4){
    float4 x = *(const float4*)(xbase + k);
    float4 a = *(const float4*)(wrow + k);
    p += a.x*x.x + a.y*x.y + a.z*x.z + a.w*x.w;
  }
  red[w][lane] = p;
  __syncthreads();
  if (t < 64){
    float s = vd1b[hh];
    #pragma unroll
    for (int ww = 0; ww < 8; ww++) s += red[ww][t];
    // packed index: row = t, col = hh
    int ks = hh >> 5, rg = t >> 4;
    int ln = (t & 15) + (((hh >> 3) & 3) << 4);
    int e  = hh & 7;
    hid_pk[(size_t)((ks * 4 + rg) * 64 + ln) * 8 + e] = f2b(s);
    out_ctx[t * 512 + hh] = ctx_ws[t * 512 + hh];
  }
}

// ---------------- K4b: p_gen only ----------------
__global__ __launch_bounds__(128) void k4b_pgen(
    const float* __restrict__ ctx_ws, const float* __restrict__ h1_ws,
    const float* __restrict__ yemb_ws,
    const float* __restrict__ pgW, const float* __restrict__ pgb,
    float* __restrict__ pgen_ws, float* __restrict__ out_pgen)
{
  __shared__ float red[128];
  int b = blockIdx.x, t = threadIdx.x;
  float p = 0.f;
  for (int i = t; i < 1152; i += 128){
    float x = (i < 512) ? ctx_ws[b * 512 + i]
            : (i < 1024) ? h1_ws[b * 512 + (i - 512)]
                         : yemb_ws[b * 128 + (i - 1024)];
    p += x * pgW[i];
  }
  red[t] = p; __syncthreads();
  for (int o = 64; o > 0; o >>= 1){ if (t < o) red[t] += red[t + o]; __syncthreads(); }
  if (t == 0){
    float pg = sigm(red[0] + pgb[0]);
    pgen_ws[b] = pg; out_pgen[b] = pg;
  }
}

// ---------------- K5: MFMA logits GEMM: [64,V] = hid[64,512] . vd2W[V,512]^T ----------------
// A from PACKED hid (1KB contiguous wave loads, L2-resident); B staged -> swizzled LDS dbuf.
__global__ __launch_bounds__(256) void k5_logits(
    const u16* __restrict__ hid_pk, const float* __restrict__ vd2W,
    const float* __restrict__ vd2b, int V, u16* __restrict__ logits_bf)
{
  __shared__ u16 blds[2][64 * 128];   // 32 KB
  int t = threadIdx.x;
  int lane = t & 63, w = t >> 6;
  int quad = lane >> 4, l16 = lane & 15;
  int cb = blockIdx.x * 64;
  f32x4 acc[4];
  #pragma unroll
  for (int rg = 0; rg < 4; rg++) acc[rg] = (f32x4){0.f,0.f,0.f,0.f};

  // staging map: 1024 groups (64 cols x 16 g8); thread handles 4 groups
  int scol0 = t >> 4, sg8 = t & 15;
  {
    #pragma unroll
    for (int i = 0; i < 4; i++){
      int col = scol0 + i * 16;
      int gr = cb + col; if (gr > V - 1) gr = V - 1;
      const float* gs = vd2W + (size_t)gr * 512 + sg8 * 8;
      float4 x = *(const float4*)gs, yv = *(const float4*)(gs + 4);
      *(bf16x8*)&blds[0][col * 128 + 8 * (sg8 ^ (col & 7))] = pack8r(x, yv);
    }
  }
  const u16* hlane = hid_pk + lane * 8;
  __syncthreads();
  int cw = w * 16 + l16;
  for (int c = 0; c < 4; c++){
    float4 px0, py0, px1, py1, px2, py2, px3, py3;
    if (c < 3){
      int kc = (c + 1) * 128;
      int g0 = cb + scol0;      if (g0 > V-1) g0 = V-1;
      int g1 = cb + scol0 + 16; if (g1 > V-1) g1 = V-1;
      int g2 = cb + scol0 + 32; if (g2 > V-1) g2 = V-1;
      int g3 = cb + scol0 + 48; if (g3 > V-1) g3 = V-1;
      const float* s0 = vd2W + (size_t)g0 * 512 + kc + sg8 * 8;
      const float* s1 = vd2W + (size_t)g1 * 512 + kc + sg8 * 8;
      const float* s2 = vd2W + (size_t)g2 * 512 + kc + sg8 * 8;
      const float* s3 = vd2W + (size_t)g3 * 512 + kc + sg8 * 8;
      px0 = *(const float4*)s0; py0 = *(const float4*)(s0 + 4);
      px1 = *(const float4*)s1; py1 = *(const float4*)(s1 + 4);
      px2 = *(const float4*)s2; py2 = *(const float4*)(s2 + 4);
      px3 = *(const float4*)s3; py3 = *(const float4*)(s3 + 4);
    }
    // batch-load all 16 A-frags for this chunk: packed, 1KB contiguous per frag
    bf16x8 aF[4][4];
    #pragma unroll
    for (int s = 0; s < 4; s++)
      #pragma unroll
      for (int rg = 0; rg < 4; rg++)
        aF[s][rg] = *(const bf16x8*)(hlane + (size_t)((c * 4 + s) * 4 + rg) * 512);
    const u16* buf = blds[c & 1];
    #pragma unroll
    for (int s = 0; s < 4; s++){
      bf16x8 bfb = *(const bf16x8*)&buf[cw * 128 + 8 * ((s * 4 + quad) ^ (cw & 7))];
      #pragma unroll
      for (int rg = 0; rg < 4; rg++)
        acc[rg] = __builtin_amdgcn_mfma_f32_16x16x32_bf16(aF[s][rg], bfb, acc[rg], 0, 0, 0);
    }
    if (c < 3){
      u16* d = (u16*)blds[(c + 1) & 1];
      *(bf16x8*)&d[scol0 * 128        + 8 * (sg8 ^ (scol0 & 7))]        = pack8r(px0, py0);
      *(bf16x8*)&d[(scol0+16) * 128   + 8 * (sg8 ^ ((scol0+16) & 7))]   = pack8r(px1, py1);
      *(bf16x8*)&d[(scol0+32) * 128   + 8 * (sg8 ^ ((scol0+32) & 7))]   = pack8r(px2, py2);
      *(bf16x8*)&d[(scol0+48) * 128   + 8 * (sg8 ^ ((scol0+48) & 7))]   = pack8r(px3, py3);
    }
    __syncthreads();
  }
  int v = cb + w * 16 + l16;
  if (v < V){
    float bias = vd2b[v];
    #pragma unroll
    for (int rg = 0; rg < 4; rg++){
      #pragma unroll
      for (int r = 0; r < 4; r++){
        int bb = rg * 16 + quad * 4 + r;
        logits_bf[(size_t)bb * V + v] = f2b(acc[rg][r] + bias);
      }
    }
  }
}

// ---------------- K6a: per-(b,chunk) max & partial sum(exp), vectorized ----------------
__global__ __launch_bounds__(256) void k6a_partial(
    const u16* __restrict__ logits_bf, int V,
    float* __restrict__ mxp, float* __restrict__ denp)
{
  __shared__ float red[256];
  int b = blockIdx.x, ch = blockIdx.y, t = threadIdx.x;
  int VG = V >> 3;                     // groups of 8 (V % 8 == 0)
  int per = (VG + 7) >> 3;             // groups per chunk (8 chunks)
  int g0 = ch * per;
  int g1 = g0 + per; if (g1 > VG) g1 = VG;
  const bf16x8* row = (const bf16x8*)(logits_bf + (size_t)b * V);
  float x[32];
  float m = -3.0e38f;
  #pragma unroll
  for (int i = 0; i < 4; i++){
    int g = g0 + t + i * 256;
    bool ok = g < g1;
    bf16x8 v;
    if (ok) v = row[g];
    #pragma unroll
    for (int j = 0; j < 8; j++){
      float f = ok ? b2f((u16)v[j]) : -3.0e38f;
      x[i * 8 + j] = f;
      m = fmaxf(m, f);
    }
  }
  red[t] = m; __syncthreads();
  for (int o = 128; o > 0; o >>= 1){ if (t < o) red[t] = fmaxf(red[t], red[t+o]); __syncthreads(); }
  float MX = red[0]; __syncthreads();
  float s = 0.f;
  #pragma unroll
  for (int k = 0; k < 32; k++) s += __expf(x[k] - MX);
  red[t] = s; __syncthreads();
  for (int o = 128; o > 0; o >>= 1){ if (t < o) red[t] += red[t+o]; __syncthreads(); }
  if (t == 0){ mxp[b * 8 + ch] = MX; denp[b * 8 + ch] = red[0]; }
}

// ---------------- K7a: out_final = p_gen * softmax(logits); combine folded in ----------------
__global__ void k7a_vocab(const u16* __restrict__ logits_bf,
    const float* __restrict__ mxp, const float* __restrict__ denp,
    const float* __restrict__ pgen_ws, int V, int VO, float* __restrict__ out_final)
{
  int b = blockIdx.y;
  // per-block recompute of the 8-partial combine (wave-uniform scalar loads)
  float MX = -3.0e38f;
  #pragma unroll
  for (int cix = 0; cix < 8; cix++) MX = fmaxf(MX, mxp[b * 8 + cix]);
  float den = 0.f;
  #pragma unroll
  for (int cix = 0; cix < 8; cix++) den += denp[b * 8 + cix] * __expf(mxp[b * 8 + cix] - MX);
  int c = (blockIdx.x * 256 + threadIdx.x) * 4;
  if (c >= VO) return;
  float inv = pgen_ws[b] / den;
  float v4[4] = {0.f, 0.f, 0.f, 0.f};
  if (c + 3 < V){
    ushort4 u = *(const ushort4*)(logits_bf + (size_t)b * V + c);
    v4[0] = inv * __expf(b2f(u.x) - MX);
    v4[1] = inv * __expf(b2f(u.y) - MX);
    v4[2] = inv * __expf(b2f(u.z) - MX);
    v4[3] = inv * __expf(b2f(u.w) - MX);
  } else {
    #pragma unroll
    for (int j = 0; j < 4; j++){
      int cc = c + j;
      if (cc < V) v4[j] = inv * __expf(b2f(logits_bf[(size_t)b * V + cc]) - MX);
    }
  }
  if (c + 4 <= VO){
    *(float4*)(out_final + (size_t)b * VO + c) = make_float4(v4[0], v4[1], v4[2], v4[3]);
  } else {
    for (int j = 0; j < 4 && c + j < VO; j++) out_final[(size_t)b * VO + c + j] = v4[j];
  }
}

// ---------------- K7b: scatter-add (1-p_gen)*attn at src_oov (fp32 atomic) ----------------
__global__ void k7b_scatter(const int* __restrict__ src_oov,
    const float* __restrict__ attn_ws, const float* __restrict__ pgen_ws,
    int VO, float* __restrict__ out_final)
{
  int idx = blockIdx.x * 256 + threadIdx.x;
  if (idx >= R_) return;
  int b = idx / S_;
  float ad = (1.0f - pgen_ws[b]) * attn_ws[idx];
  atomicAdd(&out_final[(size_t)b*VO + src_oov[idx]], ad);
}

extern "C" void kernel_launch(void* const* d_in, const int* in_sizes, int n_in,
                              void* d_out, int out_size, void* d_ws, size_t ws_size,
                              hipStream_t stream)
{
  const int*   y      = (const int*)d_in[0];
  const float* h      = (const float*)d_in[1];
  const float* mb     = (const float*)d_in[2];
  const float* mask   = (const float*)d_in[3];
  const int*   srcoov = (const int*)d_in[5];
  const float* cov    = (const float*)d_in[6];
  const float* embW   = (const float*)d_in[7];
  const float* Wih    = (const float*)d_in[8];
  const float* Whh    = (const float*)d_in[9];
  const float* bih    = (const float*)d_in[10];
  const float* bhh    = (const float*)d_in[11];
  const float* Wm     = (const float*)d_in[12];
  const float* Wd     = (const float*)d_in[13];
  const float* bd     = (const float*)d_in[14];
  const float* Wc     = (const float*)d_in[15];
  const float* av     = (const float*)d_in[16];
  const float* pgW    = (const float*)d_in[17];
  const float* pgb    = (const float*)d_in[18];
  const float* vd1W   = (const float*)d_in[19];
  const float* vd1b   = (const float*)d_in[20];
  const float* vd2W   = (const float*)d_in[21];
  const float* vd2b   = (const float*)d_in[22];

  // dynamic dims: V from vd2_b size; VO from out_size (fp32 elements):
  // out_size = B*(VO + H + M + 2S + 1)
  const int V  = in_sizes[22];
  const int VO = (int)((long long)out_size / B_ - (H_ + M_ + 2*S_ + 1));

  float* out = (float*)d_out;
  float* out_final = out;                                 // [B, VO]
  float* out_h     = out_final + (size_t)B_ * VO;         // [1,B,H]
  float* out_ctx   = out_h     + (size_t)B_ * H_;         // [B,M]
  float* out_attn  = out_ctx   + (size_t)B_ * M_;         // [B,S]
  float* out_pgen  = out_attn  + (size_t)B_ * S_;         // [B,1]
  float* out_cov   = out_pgen  + B_;                      // [B,S]

  float* ws      = (float*)d_ws;
  float* scores  = ws;                        // 25600 (dead after k3a; reused by k6 partials)
  float* h1_ws   = ws + 25600;                // 32768
  float* yemb_ws = ws + 58368;                // 8192
  float* dec_ws  = ws + 66560;                // 32768
  float* attn_ws = ws + 99328;                // 25600
  float* ctx_ws  = ws + 124928;               // 32768
  float* pgen_ws = ws + 157696;               // 64
  u16*   hid_pk    = (u16*)(ws + 157888);     // 32768 u16 (packed A-frags for k5)
  u16*   logits_bf = (u16*)(ws + 174272);     // B*V u16 (~6.4 MB)
  // wm_bf aliases the head of logits_bf: wm_bf is written by k0 and dead after
  // k2; logits_bf is first written by k5 (stream-ordered after k2).
  u16*   wm_bf     = logits_bf;               // 262144 u16 (512 KB)
  // k6 partials alias dead scores region (scores read last by k3a)
  float* mxp_ws  = scores;                    // 512
  float* denp_ws = scores + 512;              // 512

  hipLaunchKernelGGL(k0_zero,    dim3(288),  dim3(256), 0, stream,
                     ctx_ws, yemb_ws, y, embW, Wm, wm_bf);
  hipLaunchKernelGGL(k1a_gru,    dim3(512),  dim3(512), 0, stream,
                     h, yemb_ws, Wih, Whh, bih, bhh, h1_ws, out_h);
  hipLaunchKernelGGL(k1b_dec,    dim3(512),  dim3(512), 0, stream,
                     h1_ws, Wd, bd, dec_ws);
  hipLaunchKernelGGL(k2_scores,  dim3(800),  dim3(512), 0, stream,
                     mb, wm_bf, dec_ws, cov, Wc, av, scores);
  hipLaunchKernelGGL(k3a_softmax, dim3(64),  dim3(256), 0, stream,
                     scores, mask, cov, attn_ws, out_attn, out_cov);
  hipLaunchKernelGGL(k3b_ctx,    dim3(64, 16), dim3(256), 0, stream,
                     attn_ws, mb, ctx_ws);
  hipLaunchKernelGGL(k4a_hid,    dim3(512),  dim3(512), 0, stream,
                     ctx_ws, h1_ws, vd1W, vd1b, hid_pk, out_ctx);
  hipLaunchKernelGGL(k4b_pgen,   dim3(64),   dim3(128), 0, stream,
                     ctx_ws, h1_ws, yemb_ws, pgW, pgb, pgen_ws, out_pgen);
  hipLaunchKernelGGL(k5_logits,  dim3((V + 63) / 64), dim3(256), 0, stream,
                     hid_pk, vd2W, vd2b, V, logits_bf);
  hipLaunchKernelGGL(k6a_partial, dim3(64, 8), dim3(256), 0, stream,
                     logits_bf, V, mxp_ws, denp_ws);
  hipLaunchKernelGGL(k7a_vocab,  dim3((VO + 1023) / 1024, 64), dim3(256), 0, stream,
                     logits_bf, mxp_ws, denp_ws, pgen_ws, V, VO, out_final);
  hipLaunchKernelGGL(k7b_scatter, dim3(100), dim3(256), 0, stream,
                     srcoov, attn_ws, pgen_ws, VO, out_final);
}